// Round 4
// baseline (6435.539 us; speedup 1.0000x reference)
//
#include <hip/hip_runtime.h>
#include <hip/hip_fp16.h>
#include <stdint.h>

#define ALPHA 0.3f
#define NSL 12   // k-pair slices of Wh cached in LDS (of 128)

__device__ __forceinline__ float leaky(float v) { return v > 0.0f ? v : ALPHA * v; }
__device__ __forceinline__ float sigm(float v)  { return 1.0f / (1.0f + __expf(-v)); }
__device__ __forceinline__ float tanh_fast(float v) { return 1.0f - 2.0f / (1.0f + __expf(2.0f * v)); }
__device__ __forceinline__ __half2 u2h(unsigned u) { union { unsigned u; __half2 h; } c; c.u = u; return c.h; }

// ---------------------------------------------------------------------------
// Pack Wh (256x1024) and Wx (51x1024) fp32 -> fp16 k-pair-packed, gate-interleaved.
// Whp u32[idx], idx = kp*1024 + j*4 + g  = half2( Wh[2kp][g*256+j], Wh[2kp+1][g*256+j] )
// Wxp u32[i],   i   = fp*1024 + j*4 + g  = half2( Wx[2fp][g*256+j], Wx[2fp+1][g*256+j] ), f=51 -> 0
// ---------------------------------------------------------------------------
__global__ __launch_bounds__(256) void pack_w(
    const float* __restrict__ Wh, const float* __restrict__ Wx,
    unsigned* __restrict__ Whp, unsigned* __restrict__ Wxp) {
    int idx = blockIdx.x * 256 + threadIdx.x;
    if (idx < 128 * 1024) {
        int kp = idx >> 10, rem = idx & 1023;
        int j = rem >> 2, g = rem & 3;
        int col = g * 256 + j;
        float a = Wh[(2 * kp) * 1024 + col];
        float b = Wh[(2 * kp + 1) * 1024 + col];
        Whp[idx] = (unsigned)__half_as_ushort(__float2half(a))
                 | ((unsigned)__half_as_ushort(__float2half(b)) << 16);
    } else {
        int i = idx - 128 * 1024;   // grid sized exactly: i < 26*1024
        int fp = i >> 10, rem = i & 1023;
        int j = rem >> 2, g = rem & 3;
        int col = g * 256 + j;
        float a = Wx[(2 * fp) * 1024 + col];
        float b = (2 * fp + 1 < 51) ? Wx[(2 * fp + 1) * 1024 + col] : 0.0f;
        Wxp[i] = (unsigned)__half_as_ushort(__float2half(a))
               | ((unsigned)__half_as_ushort(__float2half(b)) << 16);
    }
}

// ---------------------------------------------------------------------------
// Fused conv1 -> conv2 -> partial dense dot. One block per batch element.
// h1 lives only in LDS. Writes out[b] = conv_dot + bd.
// Dynamic LDS: h1s = 16384 floats, xs = 13212 floats  (118384 B)
// ---------------------------------------------------------------------------
__global__ __launch_bounds__(256) void conv_kernel(
    const float* __restrict__ x,
    const float* __restrict__ k1, const float* __restrict__ b1,
    const float* __restrict__ k2, const float* __restrict__ b2,
    const float* __restrict__ Wd, const float* __restrict__ bd,
    float* __restrict__ out) {
    extern __shared__ unsigned char smem[];
    float* h1s = (float*)smem;                 // 65536 B
    float* xs  = (float*)(smem + 65536);       // 52848 B

    const int tid = threadIdx.x;
    const int b   = blockIdx.x;
    const float* xb = x + (size_t)b * (512 * 51);

    const int c1g = tid & 15;   // 16 groups * 4 c1
    const int t1g = tid >> 4;   // 16 groups * 8 t1
    float4 b1v = *(const float4*)&b1[c1g * 4];

    #pragma unroll
    for (int chunk = 0; chunk < 2; ++chunk) {
        const int tb   = chunk ? 128 : 0;
        const int rb   = chunk ? 252 : 0;
        const int rows = chunk ? 259 : 255;
        {
            const float* src = xb + rb * 51;
            int total = rows * 51;
            int n4 = total >> 2;
            const float4* s4 = (const float4*)src;
            float4* d4 = (float4*)xs;
            for (int i = tid; i < n4; i += 256) d4[i] = s4[i];
            for (int i = (n4 << 2) + tid; i < total; i += 256) xs[i] = src[i];
        }
        __syncthreads();

        float acc[8][4];
        #pragma unroll
        for (int i = 0; i < 8; ++i) { acc[i][0]=0.f; acc[i][1]=0.f; acc[i][2]=0.f; acc[i][3]=0.f; }

        for (int w = 0; w < 5; ++w) {
            for (int f = 0; f < 51; ++f) {
                float4 wt = *(const float4*)&k1[(w * 51 + f) * 64 + c1g * 4];
                #pragma unroll
                for (int i = 0; i < 8; ++i) {
                    int t1 = tb + t1g * 8 + i;
                    int r = 2 * t1 + w - 4;
                    if (r >= rb) {
                        float a = xs[(r - rb) * 51 + f];
                        acc[i][0] += a * wt.x; acc[i][1] += a * wt.y;
                        acc[i][2] += a * wt.z; acc[i][3] += a * wt.w;
                    }
                }
            }
        }
        #pragma unroll
        for (int i = 0; i < 8; ++i) {
            int t1 = tb + t1g * 8 + i;
            float* dst = &h1s[t1 * 64 + c1g * 4];
            dst[0] = leaky(acc[i][0] + b1v.x);
            dst[1] = leaky(acc[i][1] + b1v.y);
            dst[2] = leaky(acc[i][2] + b1v.z);
            dst[3] = leaky(acc[i][3] + b1v.w);
        }
        __syncthreads();
    }

    // conv2: thread owns 4 c2 x 16 t2
    const int c2g = tid & 31;
    const int t2g = tid >> 5;
    float acc2[16][4];
    #pragma unroll
    for (int i = 0; i < 16; ++i) { acc2[i][0]=0.f; acc2[i][1]=0.f; acc2[i][2]=0.f; acc2[i][3]=0.f; }

    for (int w = 0; w < 5; ++w) {
        for (int c1 = 0; c1 < 64; ++c1) {
            float4 wt = *(const float4*)&k2[(w * 64 + c1) * 128 + c2g * 4];
            #pragma unroll
            for (int i = 0; i < 16; ++i) {
                int t2 = t2g * 16 + i;
                int r = 2 * t2 + w - 4;
                if (r >= 0) {
                    float a = h1s[r * 64 + c1];
                    acc2[i][0] += a * wt.x; acc2[i][1] += a * wt.y;
                    acc2[i][2] += a * wt.z; acc2[i][3] += a * wt.w;
                }
            }
        }
    }

    float4 b2v = *(const float4*)&b2[c2g * 4];
    float p = 0.f;
    #pragma unroll
    for (int i = 0; i < 16; ++i) {
        int t2 = t2g * 16 + i;
        float4 wd = *(const float4*)&Wd[256 + t2 * 128 + c2g * 4];
        p += leaky(acc2[i][0] + b2v.x) * wd.x;
        p += leaky(acc2[i][1] + b2v.y) * wd.y;
        p += leaky(acc2[i][2] + b2v.z) * wd.z;
        p += leaky(acc2[i][3] + b2v.w) * wd.w;
    }

    float* red = xs;
    __syncthreads();
    red[tid] = p;
    __syncthreads();
    for (int s = 128; s > 0; s >>= 1) {
        if (tid < s) red[tid] += red[tid + s];
        __syncthreads();
    }
    if (tid == 0) out[b] = red[0] + bd[0];
}

// ---------------------------------------------------------------------------
// Persistent LSTM: 256 blocks x 4 batch rows. Thread j owns h-column j
// (gates j, j+256, j+512, j+768) for its 4 rows -> c/h update register-local.
// fp16 k-pair-packed weights; __hfma2 packed math (2 FMA/lane/inst).
// Wx + NSL k-pair slices of Wh LDS-resident; rest streamed from L2.
// x[t+1] prefetched into a register during step t's compute phase.
// Adds leaky(h_final) . Wd[0:256] into out[b].
// Dynamic LDS layout (bytes): wx_l 106496 | wh_l NSL*4096 | h16 2048 | xt16 416
// ---------------------------------------------------------------------------
__global__ __launch_bounds__(256) void lstm_kernel(
    const float* __restrict__ x,
    const uint4*  __restrict__ Whp,    // 128 kp * 256 j * 16B (4 gates)
    const uint4*  __restrict__ Wxp,    // 26 fp * 256 j * 16B
    const float*  __restrict__ bl,
    const float*  __restrict__ Wd,
    float* __restrict__ out) {
    extern __shared__ unsigned char smem[];
    unsigned* wx_l = (unsigned*)smem;                            // 26*1024 u32
    unsigned* wh_l = (unsigned*)(smem + 106496);                 // NSL*1024 u32
    unsigned* h16  = (unsigned*)(smem + 106496 + NSL * 4096);    // 512 u32
    unsigned* xt16 = (unsigned*)(smem + 106496 + NSL * 4096 + 2048); // 104 u32

    const int j  = threadIdx.x;
    const int b0 = blockIdx.x * 4;

    {
        uint4* d = (uint4*)wx_l;
        for (int i = j; i < 26 * 256; i += 256) d[i] = Wxp[i];
        uint4* dw = (uint4*)wh_l;
        for (int i = j; i < NSL * 256; i += 256) dw[i] = Whp[i];
    }
    h16[j] = 0; h16[j + 256] = 0;
    if (j < 104) xt16[j] = 0;               // hi half of fp=25 (f=51) stays 0 forever
    const float bz0 = bl[j], bz1 = bl[j + 256], bz2 = bl[j + 512], bz3 = bl[j + 768];
    float cc[4] = {0.f, 0.f, 0.f, 0.f};
    float hn[4] = {0.f, 0.f, 0.f, 0.f};
    unsigned short* h16s  = (unsigned short*)h16;
    unsigned short* xt16s = (unsigned short*)xt16;

    // x prefetch state: thread j<204 owns (row r, feature f)
    const int fx = j >> 2, rx = j & 3;
    const float* xptr = x + ((size_t)(b0 + rx) * 512) * 51 + fx;
    float xpre = (j < 204) ? xptr[0] : 0.0f;
    __syncthreads();

    for (int t = 0; t < 512; ++t) {
        if (j < 204)
            xt16s[(fx >> 1) * 8 + rx * 2 + (fx & 1)] = __half_as_ushort(__float2half(xpre));
        __syncthreads();   // A: publishes xt16 and h16 (written end of prev iter)

        // issue next step's x load; consumed after barrier B -> latency hidden
        float xnext = 0.0f;
        if (j < 204 && t + 1 < 512) xnext = xptr[(t + 1) * 51];

        __half2 acc[4][4];
        #pragma unroll
        for (int r = 0; r < 4; ++r)
            #pragma unroll
            for (int g = 0; g < 4; ++g) acc[r][g] = u2h(0u);

        // x-projection (Wx in LDS)
        #pragma unroll 2
        for (int fp = 0; fp < 26; ++fp) {
            uint4 wq = ((const uint4*)wx_l)[fp * 256 + j];
            uint4 hq = *(const uint4*)&xt16[fp * 4];            // broadcast
            __half2 xv[4] = {u2h(hq.x), u2h(hq.y), u2h(hq.z), u2h(hq.w)};
            __half2 wv[4] = {u2h(wq.x), u2h(wq.y), u2h(wq.z), u2h(wq.w)};
            #pragma unroll
            for (int r = 0; r < 4; ++r)
                #pragma unroll
                for (int g = 0; g < 4; ++g)
                    acc[r][g] = __hfma2(xv[r], wv[g], acc[r][g]);
        }

        // recurrent GEMM part 1: LDS-resident Wh slices
        #pragma unroll 4
        for (int kp = 0; kp < NSL; ++kp) {
            uint4 wq = ((const uint4*)wh_l)[kp * 256 + j];
            uint4 hq = *(const uint4*)&h16[kp * 4];             // broadcast
            __half2 hv[4] = {u2h(hq.x), u2h(hq.y), u2h(hq.z), u2h(hq.w)};
            __half2 wv[4] = {u2h(wq.x), u2h(wq.y), u2h(wq.z), u2h(wq.w)};
            #pragma unroll
            for (int r = 0; r < 4; ++r)
                #pragma unroll
                for (int g = 0; g < 4; ++g)
                    acc[r][g] = __hfma2(hv[r], wv[g], acc[r][g]);
        }
        // part 2: streamed from L2, 8 loads in flight
        #pragma unroll 8
        for (int kp = NSL; kp < 128; ++kp) {
            uint4 wq = Whp[kp * 256 + j];
            uint4 hq = *(const uint4*)&h16[kp * 4];
            __half2 hv[4] = {u2h(hq.x), u2h(hq.y), u2h(hq.z), u2h(hq.w)};
            __half2 wv[4] = {u2h(wq.x), u2h(wq.y), u2h(wq.z), u2h(wq.w)};
            #pragma unroll
            for (int r = 0; r < 4; ++r)
                #pragma unroll
                for (int g = 0; g < 4; ++g)
                    acc[r][g] = __hfma2(hv[r], wv[g], acc[r][g]);
        }

        // gates + state update (Keras order i,f,g,o)
        #pragma unroll
        for (int r = 0; r < 4; ++r) {
            float zi = __low2float(acc[r][0]) + __high2float(acc[r][0]) + bz0;
            float zf = __low2float(acc[r][1]) + __high2float(acc[r][1]) + bz1;
            float zg = __low2float(acc[r][2]) + __high2float(acc[r][2]) + bz2;
            float zo = __low2float(acc[r][3]) + __high2float(acc[r][3]) + bz3;
            float iv = sigm(zi);
            float fv = sigm(zf);
            float gv = tanh_fast(zg);
            float ov = sigm(zo);
            cc[r] = fv * cc[r] + iv * gv;
            hn[r] = ov * tanh_fast(cc[r]);
        }
        __syncthreads();   // B: all reads of h16/xt16 this step done
        xpre = xnext;
        #pragma unroll
        for (int r = 0; r < 4; ++r)
            h16s[(j >> 1) * 8 + r * 2 + (j & 1)] = __half_as_ushort(__float2half(hn[r]));
        // next iteration's barrier A publishes h16/xt16 before any read
    }

    // out[b] += leaky(h) . Wd[0:256]
    const float pw = Wd[j];
    float p0 = leaky(hn[0]) * pw;
    float p1 = leaky(hn[1]) * pw;
    float p2 = leaky(hn[2]) * pw;
    float p3 = leaky(hn[3]) * pw;
    float* red = (float*)wh_l;   // reuse (all wh_l reads are behind the last barrier)
    __syncthreads();
    *(float4*)&red[j * 4] = make_float4(p0, p1, p2, p3);
    __syncthreads();
    for (int s = 128; s > 0; s >>= 1) {
        if (j < s) {
            float4 a = *(const float4*)&red[j * 4];
            float4 c = *(const float4*)&red[(j + s) * 4];
            a.x += c.x; a.y += c.y; a.z += c.z; a.w += c.w;
            *(float4*)&red[j * 4] = a;
        }
        __syncthreads();
    }
    if (j < 4) out[b0 + j] += red[j];
}

// ---------------------------------------------------------------------------
extern "C" void kernel_launch(void* const* d_in, const int* in_sizes, int n_in,
                              void* d_out, int out_size, void* d_ws, size_t ws_size,
                              hipStream_t stream) {
    const float* x   = (const float*)d_in[0];
    const float* Wx  = (const float*)d_in[1];
    const float* Wh  = (const float*)d_in[2];
    const float* bl  = (const float*)d_in[3];
    const float* k1  = (const float*)d_in[4];
    const float* b1  = (const float*)d_in[5];
    const float* k2  = (const float*)d_in[6];
    const float* b2  = (const float*)d_in[7];
    const float* Wd  = (const float*)d_in[8];
    const float* bd  = (const float*)d_in[9];
    float* out = (float*)d_out;

    unsigned* Whp = (unsigned*)d_ws;           // 131072 u32 (512 KB)
    unsigned* Wxp = Whp + 128 * 1024;          //  26624 u32 (104 KB)

    const int conv_smem = 65536 + 13212 * 4;                       // 118384 B
    const int lstm_smem = 106496 + NSL * 4096 + 2048 + 416;        // 158112 B

    // Unconditional (idempotent) — no static guards, graph-capture-safe:
    // host-side function-attribute calls, not stream operations.
    hipFuncSetAttribute((const void*)conv_kernel,
                        hipFuncAttributeMaxDynamicSharedMemorySize, conv_smem);
    hipFuncSetAttribute((const void*)lstm_kernel,
                        hipFuncAttributeMaxDynamicSharedMemorySize, lstm_smem);

    pack_w<<<616, 256, 0, stream>>>(Wh, Wx, Whp, Wxp);
    conv_kernel<<<1024, 256, conv_smem, stream>>>(x, k1, b1, k2, b2, Wd, bd, out);
    lstm_kernel<<<256, 256, lstm_smem, stream>>>(x, (const uint4*)Whp, (const uint4*)Wxp,
                                                 bl, Wd, out);
}